// Round 3
// baseline (361.041 us; speedup 1.0000x reference)
//
#include <hip/hip_runtime.h>

// CostVolume2D: N=8, C=128, H=96, W=224, D=4 -> 81 channels.
// out[n, dy*9+dx, h, w] = mean_c f1[n,c,h,w] * f2[n,c,h+dy-4,w+dx-4] (0 if OOB)
//
// Round 3: (a) XCD swizzle -- the 3 dy-group blocks of one tile share an XCD
// (b = ((tp*3+dyg)<<3)|xcd) so f1/f2 re-reads hit that XCD's L2 instead of
// tripling HBM traffic (round-2 FETCH was 443 MB vs ~180 ideal).
// (b) 2-channel unroll + double-buffered LDS -> ONE __syncthreads per 2
// channels (was 2 per channel); prefetch loads are a full iteration old at
// the barrier's vmcnt(0) drain, covering L2 latency.
//
// Block = 192 threads (3 waves), tile 32(w) x 16(h). Wave wb handles
// dy = 3*dyg + wb. Per thread: 8w x 1h px x 9 dx = 72 fp32 accumulators.

constexpr int Cn = 128;
constexpr int Hh = 96;
constexpr int Ww = 224;
constexpr int HW = Hh * Ww;       // 21504
constexpr int TILE_H = 16;
constexpr int TILE_W = 32;
constexpr int F2R = 18;           // TILE_H + 2 (3 dy span)
constexpr int F2S = 44;           // row stride: 8 lanes/16B-seg, uniform
constexpr int CT  = F2R * F2S;    // 792 floats per channel tile

__global__ __launch_bounds__(192, 3)
void costvol_kernel(const float* __restrict__ f1g, const float* __restrict__ f2g,
                    float* __restrict__ outg) {
    __shared__ float lds[2][2][CT];    // [buf][ch-of-pair][tile] = 12672 B

    const int b    = blockIdx.x;
    const int xcd  = b & 7;            // XCD (consecutive IDs round-robin XCDs)
    const int j    = b >> 3;           // 0..125
    const int dyg  = j % 3;
    const int tp   = j / 3;            // 0..41
    const int tile = tp * 8 + xcd;     // 0..335: same tile's 3 dygs same XCD
    const int wt   = tile % 7;
    const int ht   = (tile / 7) % 6;
    const int n    = tile / 42;

    const int h0 = ht * TILE_H;
    const int w0 = wt * TILE_W;
    const int d0 = dyg * 3;

    const int tid  = threadIdx.x;
    const int wb   = tid >> 6;         // wave id = dy offset in group
    const int lane = tid & 63;
    const int gx   = lane & 3;         // 8 w px: w = w0 + 8*gx + (0..7)
    const int gy   = lane >> 2;        // h row: h = h0 + gy

    // ---- staging: 180 float4 slots cover 18 rows x 10 groups (per channel) ----
    const int  srow = tid / 10;
    const int  sg   = tid - srow * 10;
    const bool sAct = (tid < 180);
    const int  yS   = h0 + d0 - 4 + srow;
    const int  xS   = w0 - 4 + 4 * sg;          // float4 granule, never straddles W
    const bool sVal = sAct && (yS >= 0) && (yS < Hh) && (xS >= 0) && (xS < Ww);
    const int  sOff = sVal ? (yS * Ww + xS) : 0;
    const int  sLds = srow * F2S + 4 * sg;

    const size_t nbase = (size_t)n * Cn * HW;
    const float* f1n = f1g + nbase;
    const float* f2n = f2g + nbase;

    const int hA    = h0 + gy;
    const int wA    = w0 + 8 * gx;
    const int f1off = hA * Ww + wA;
    const int ldsr  = (gy + wb) * F2S + 8 * gx;

    float4 acc[2][9];
#pragma unroll
    for (int p = 0; p < 2; ++p)
#pragma unroll
        for (int dx = 0; dx < 9; ++dx)
            acc[p][dx] = make_float4(0.f, 0.f, 0.f, 0.f);

    const float4 z4 = make_float4(0.f, 0.f, 0.f, 0.f);

    // prefetch channel pair 0
    float4 st[2], f1c[2][2], f1nx[2][2];
    st[0] = sVal ? *(const float4*)(f2n + sOff) : z4;
    st[1] = sVal ? *(const float4*)(f2n + HW + sOff) : z4;
    f1c[0][0] = *(const float4*)(f1n + f1off);
    f1c[0][1] = *(const float4*)(f1n + f1off + 4);
    f1c[1][0] = *(const float4*)(f1n + HW + f1off);
    f1c[1][1] = *(const float4*)(f1n + HW + f1off + 4);

#pragma unroll 2
    for (int cp = 0; cp < Cn / 2; ++cp) {
        float* bufp = &lds[cp & 1][0][0];
        if (sAct) {
            *(float4*)(bufp + sLds)      = st[0];
            *(float4*)(bufp + CT + sLds) = st[1];
        }
        __syncthreads();               // ONE barrier per 2 channels (dbuf:
                                       // next write targets the other buffer)

        // issue loads for pair cp+1 AFTER the barrier so its vmcnt(0) drain
        // only covers pair-cp loads (a full iteration old -> complete).
        if (cp + 1 < Cn / 2) {
            const float* f2c = f2n + (size_t)(2 * cp + 2) * HW;
            st[0] = sVal ? *(const float4*)(f2c + sOff) : z4;
            st[1] = sVal ? *(const float4*)(f2c + HW + sOff) : z4;
            const float* f1p = f1n + (size_t)(2 * cp + 2) * HW + f1off;
            f1nx[0][0] = *(const float4*)(f1p);
            f1nx[0][1] = *(const float4*)(f1p + 4);
            f1nx[1][0] = *(const float4*)(f1p + HW);
            f1nx[1][1] = *(const float4*)(f1p + HW + 4);
        }

#pragma unroll
        for (int e = 0; e < 2; ++e) {
            // f2 window: row gy+wb, cols [8gx, 8gx+16) -- 4 aligned b128
            const float* lr = bufp + e * CT + ldsr;
            const float4 q0 = *(const float4*)(lr);
            const float4 q1 = *(const float4*)(lr + 4);
            const float4 q2 = *(const float4*)(lr + 8);
            const float4 q3 = *(const float4*)(lr + 12);
            const float wv[16] = {q0.x, q0.y, q0.z, q0.w,
                                  q1.x, q1.y, q1.z, q1.w,
                                  q2.x, q2.y, q2.z, q2.w,
                                  q3.x, q3.y, q3.z, q3.w};
            const float4 a0 = f1c[e][0];
            const float4 a1 = f1c[e][1];
#pragma unroll
            for (int dx = 0; dx < 9; ++dx) {
                acc[0][dx].x += a0.x * wv[dx + 0];
                acc[0][dx].y += a0.y * wv[dx + 1];
                acc[0][dx].z += a0.z * wv[dx + 2];
                acc[0][dx].w += a0.w * wv[dx + 3];
                acc[1][dx].x += a1.x * wv[dx + 4];
                acc[1][dx].y += a1.y * wv[dx + 5];
                acc[1][dx].z += a1.z * wv[dx + 6];
                acc[1][dx].w += a1.w * wv[dx + 7];
            }
        }
#pragma unroll
        for (int e = 0; e < 2; ++e) {
            f1c[e][0] = f1nx[e][0];
            f1c[e][1] = f1nx[e][1];
        }
    }

    // ---- writeout: 2 x 9 float4 per thread, coalesced 16B stores ----
    const float sc = 1.0f / 128.0f;
    const int dy = d0 + wb;
    float* ob = outg + (size_t)n * 81 * HW + (size_t)hA * Ww + wA;
#pragma unroll
    for (int dx = 0; dx < 9; ++dx) {
        const int k = dy * 9 + dx;
#pragma unroll
        for (int p = 0; p < 2; ++p) {
            float4 v = acc[p][dx];
            v.x *= sc; v.y *= sc; v.z *= sc; v.w *= sc;
            *(float4*)(ob + (size_t)k * HW + 4 * p) = v;
        }
    }
}

extern "C" void kernel_launch(void* const* d_in, const int* in_sizes, int n_in,
                              void* d_out, int out_size, void* d_ws, size_t ws_size,
                              hipStream_t stream) {
    const float* f1 = (const float*)d_in[0];
    const float* f2 = (const float*)d_in[1];
    float* out = (float*)d_out;
    // grid: 336 tiles x 3 dy-groups, swizzled so a tile's 3 blocks share an XCD
    costvol_kernel<<<dim3(1008), dim3(192), 0, stream>>>(f1, f2, out);
}

// Round 4
// 270.936 us; speedup vs baseline: 1.3326x; 1.3326x over previous
//
#include <hip/hip_runtime.h>

// CostVolume2D: N=8, C=128, H=96, W=224, D=4 -> 81 channels.
// out[n, dy*9+dx, h, w] = mean_c f1[n,c,h,w] * f2[n,c,h+dy-4,w+dx-4] (0 if OOB)
//
// Round 4 = round-2 body (spill-free, 60 VGPR) + two proven/cheap changes:
//  (a) XCD swizzle: a tile's 3 dy-group blocks share an XCD -> f1/f2 re-reads
//      hit L2 (round-3 verified: FETCH 443 -> 189 MB).
//  (b) double-buffered LDS -> ONE __syncthreads per channel (was 2); the
//      prefetch loads are a full iteration old at the barrier drain.
// Round 3's channel-pairing spilled 3 float4/iter to scratch (WRITE_SIZE
// 57 -> 205 MB) -- reverted. Keep live prefetch state minimal: st + f1r only.
//
// Block = 192 threads (3 waves), tile 32(w) x 16(h). Wave wb handles
// dy = 3*dyg + wb. Per thread: 8w x 1h px x 9 dx = 72 fp32 accumulators.

constexpr int Cn = 128;
constexpr int Hh = 96;
constexpr int Ww = 224;
constexpr int HW = Hh * Ww;       // 21504
constexpr int TILE_H = 16;
constexpr int TILE_W = 32;
constexpr int F2R = 18;           // TILE_H + 2 (3 dy span)
constexpr int F2S = 44;           // row stride: pad 40->44 for bank spread
constexpr int CT  = F2R * F2S;    // 792 floats per channel tile

__global__ __launch_bounds__(192, 3)
void costvol_kernel(const float* __restrict__ f1g, const float* __restrict__ f2g,
                    float* __restrict__ outg) {
    __shared__ float lds[2][CT];       // double buffer, 6336 B

    const int b    = blockIdx.x;
    const int xcd  = b & 7;            // consecutive block IDs round-robin XCDs
    const int j    = b >> 3;           // 0..125
    const int dyg  = j % 3;
    const int tp   = j / 3;            // 0..41
    const int tile = tp * 8 + xcd;     // same tile's 3 dy-groups -> same XCD
    const int wt   = tile % 7;
    const int ht   = (tile / 7) % 6;
    const int n    = tile / 42;

    const int h0 = ht * TILE_H;
    const int w0 = wt * TILE_W;
    const int d0 = dyg * 3;

    const int tid  = threadIdx.x;
    const int wb   = tid >> 6;         // wave id = dy offset in group
    const int lane = tid & 63;
    const int gx   = lane & 3;         // 8 w px: w = w0 + 8*gx + (0..7)
    const int gy   = lane >> 2;        // h row: h = h0 + gy

    // ---- staging: 180 float4 slots cover 18 rows x 10 groups ----
    const int  srow = tid / 10;
    const int  sg   = tid - srow * 10;
    const bool sAct = (tid < 180);
    const int  yS   = h0 + d0 - 4 + srow;
    const int  xS   = w0 - 4 + 4 * sg;        // float4 granule, never straddles W
    const bool sVal = sAct && (yS >= 0) && (yS < Hh) && (xS >= 0) && (xS < Ww);
    const int  sOff = sVal ? (yS * Ww + xS) : 0;
    const int  sLds = srow * F2S + 4 * sg;

    const size_t nbase = (size_t)n * Cn * HW;
    const float* f1n = f1g + nbase;
    const float* f2n = f2g + nbase;

    const int hA    = h0 + gy;
    const int wA    = w0 + 8 * gx;
    const int f1off = hA * Ww + wA;
    const int ldsr  = (gy + wb) * F2S + 8 * gx;

    float4 acc[2][9];
#pragma unroll
    for (int p = 0; p < 2; ++p)
#pragma unroll
        for (int dx = 0; dx < 9; ++dx)
            acc[p][dx] = make_float4(0.f, 0.f, 0.f, 0.f);

    const float4 z4 = make_float4(0.f, 0.f, 0.f, 0.f);

    // prefetch c = 0
    float4 st, f1r0, f1r1;
    st   = sVal ? *(const float4*)(f2n + sOff) : z4;
    f1r0 = *(const float4*)(f1n + f1off);
    f1r1 = *(const float4*)(f1n + f1off + 4);

#pragma unroll 1
    for (int c = 0; c < Cn; ++c) {
        float* bufp = &lds[c & 1][0];
        if (sAct) *(float4*)(bufp + sLds) = st;
        __syncthreads();               // single barrier: next write goes to the
                                       // OTHER buffer; reads of buf (c&1) from
                                       // iter c-2 are fenced by barrier c-1

        const float4 a0 = f1r0;
        const float4 a1 = f1r1;

        // prefetch c+1 (consumed at iter c+1's top -> full iteration of slack)
        if (c + 1 < Cn) {
            const float* f2c = f2n + (size_t)(c + 1) * HW;
            st = sVal ? *(const float4*)(f2c + sOff) : z4;
            const float* f1p = f1n + (size_t)(c + 1) * HW + f1off;
            f1r0 = *(const float4*)(f1p);
            f1r1 = *(const float4*)(f1p + 4);
        }

        // f2 window: row gy+wb, cols [8gx, 8gx+16) -- 4 aligned b128
        const float* lr = bufp + ldsr;
        const float4 q0 = *(const float4*)(lr);
        const float4 q1 = *(const float4*)(lr + 4);
        const float4 q2 = *(const float4*)(lr + 8);
        const float4 q3 = *(const float4*)(lr + 12);
        const float wv[16] = {q0.x, q0.y, q0.z, q0.w,
                              q1.x, q1.y, q1.z, q1.w,
                              q2.x, q2.y, q2.z, q2.w,
                              q3.x, q3.y, q3.z, q3.w};

        // px w = 8gx + 4p + j needs f2 col (w-4+dx) -> wv[4p + dx + j]
#pragma unroll
        for (int dx = 0; dx < 9; ++dx) {
            acc[0][dx].x += a0.x * wv[dx + 0];
            acc[0][dx].y += a0.y * wv[dx + 1];
            acc[0][dx].z += a0.z * wv[dx + 2];
            acc[0][dx].w += a0.w * wv[dx + 3];
            acc[1][dx].x += a1.x * wv[dx + 4];
            acc[1][dx].y += a1.y * wv[dx + 5];
            acc[1][dx].z += a1.z * wv[dx + 6];
            acc[1][dx].w += a1.w * wv[dx + 7];
        }
    }

    // ---- writeout: 2 x 9 float4 per thread, coalesced 16B stores ----
    const float sc = 1.0f / 128.0f;
    const int dy = d0 + wb;
    float* ob = outg + (size_t)n * 81 * HW + (size_t)hA * Ww + wA;
#pragma unroll
    for (int dx = 0; dx < 9; ++dx) {
        const int k = dy * 9 + dx;
#pragma unroll
        for (int p = 0; p < 2; ++p) {
            float4 v = acc[p][dx];
            v.x *= sc; v.y *= sc; v.z *= sc; v.w *= sc;
            *(float4*)(ob + (size_t)k * HW + 4 * p) = v;
        }
    }
}

extern "C" void kernel_launch(void* const* d_in, const int* in_sizes, int n_in,
                              void* d_out, int out_size, void* d_ws, size_t ws_size,
                              hipStream_t stream) {
    const float* f1 = (const float*)d_in[0];
    const float* f2 = (const float*)d_in[1];
    float* out = (float*)d_out;
    // grid: 336 tiles x 3 dy-groups, swizzled so a tile's 3 blocks share an XCD
    costvol_kernel<<<dim3(1008), dim3(192), 0, stream>>>(f1, f2, out);
}